// Round 12
// baseline (346.202 us; speedup 1.0000x reference)
//
#include <hip/hip_runtime.h>
#include <math.h>

// ===========================================================================
// PCSQCNN fully fused: FRQI encode -> [QFT2D -> mux -> IQFT2D -> pool]^3
//                      -> |.|^2 -> linear   (linear head fused)
//
// History: r10 fused kfuse; r11-r16+r20 EIGHT allocator levers -> all null
// (VGPR=64 immovable for 1024-thr blocks; ~230MB scratch round-trip,
// partially hidden by 2 WG/CU). r18 LDS b64 -> regression. r19 fused head
// -> 339.8us (best). r20 parallel tail + launch_bounds(1024,1) -> null
// (kfuse identical 292.5 vs 292.4). ds_bpermute exchange analysed: source
// slot is lane-varying for these ownerships -> not applicable.
//
// Round 21 (this round): NONTEMPORAL image loads. img (33.5MB/iter) is
// streamed once but pollutes L2 - the cache tier hiding the scratch
// round-trip. __builtin_nontemporal_load on the 16 encode loads keeps
// scratch lines resident. Everything else byte-identical to r20.
//
// U tables (k0): U0 transposed [y_st][x_st]; U1 unchanged;
// U2 stored [yam][cx][cy][xam]. Ownerships: F = {2j,2j+1,64+2j,65+2j};
// F4 = {fb,fb+16,fb+64,fb+80}, fb=(j>>4)*32+(j&15).
// ===========================================================================

#define PI_F 3.14159265358979323846f
#define P_ 128

__device__ __forceinline__ float2 cmul(float2 a, float2 b) {
    return make_float2(a.x * b.x - a.y * b.y, a.x * b.y + a.y * b.x);
}
__device__ __forceinline__ float2 cadd(float2 a, float2 b) {
    return make_float2(a.x + b.x, a.y + b.y);
}
__device__ __forceinline__ float2 scl(float2 a, float s) {
    return make_float2(a.x * s, a.y * s);
}
// DIF butterfly: u' = u+v ; v' = (u-v)*w
__device__ __forceinline__ void bfly_dif(float2& u, float2& v, float2 w) {
    float tx = u.x - v.x, ty = u.y - v.y;
    u.x += v.x; u.y += v.y;
    v.x = tx * w.x - ty * w.y;
    v.y = tx * w.y + ty * w.x;
}
__device__ __forceinline__ void bfly_dif1(float2& u, float2& v) {
    float tx = u.x - v.x, ty = u.y - v.y;
    u.x += v.x; u.y += v.y;
    v.x = tx; v.y = ty;
}
// DIT inverse butterfly: t = v*conj(w); u' = u+t ; v' = u-t
__device__ __forceinline__ void bfly_dit(float2& u, float2& v, float2 w) {
    float tx = v.x * w.x + v.y * w.y, ty = v.y * w.x - v.x * w.y;
    v.x = u.x - tx; v.y = u.y - ty;
    u.x += tx; u.y += ty;
}
__device__ __forceinline__ void bfly_dit1(float2& u, float2& v) {
    float tx = v.x, ty = v.y;
    v.x = u.x - tx; v.y = u.y - ty;
    u.x += tx; u.y += ty;
}

constexpr int clog2(int v) { return v <= 1 ? 0 : 1 + clog2(v >> 1); }

// LDS exchange address: line L (0..63 per plane), idx 0..127, XOR bank
// swizzle (bijective; GF(2)-rank-verified for all ownership patterns).
__device__ __forceinline__ int pf(int L, int idx) {
    int m = ((idx & 32) ? 13 : 0) ^ ((idx & 64) ? 22 : 0);
    return L * P_ + (idx ^ m);
}

// Ownership: segment size N (<=128), stride S. Thread j (0..31 per line) owns
// idx[q] = seg*N + 4S*(jj/S) + (jj%S) + S*q.  o = jj%S (twiddle low part).
template <int N, int S>
__device__ __forceinline__ void oidx(int j, int i[4], int& o) {
    constexpr int TPS = N / 4;
    constexpr int LT = clog2(TPS);
    int s = j >> LT;
    int jj = j & (TPS - 1);
    o = jj & (S - 1);
    int base = s * N + ((jj & ~(S - 1)) << 2) + o;
    i[0] = base; i[1] = base + S; i[2] = base + 2 * S; i[3] = base + 3 * S;
}

// Two DIF levels h=2S then h=S on r[0..3] (ownership stride S)
template <int S>
__device__ __forceinline__ void dif_pair(float2 r[4], int o, const float2* tw) {
    bfly_dif(r[0], r[2], tw[o * (32 / S)]);
    bfly_dif(r[1], r[3], tw[(o + S) * (32 / S)]);
    float2 wc = tw[o * (64 / S)];
    bfly_dif(r[0], r[1], wc);
    bfly_dif(r[2], r[3], wc);
}
// Two DIT levels h=S then h=2S
template <int S>
__device__ __forceinline__ void dit_pair(float2 r[4], int o, const float2* tw) {
    float2 wc = tw[o * (64 / S)];
    bfly_dit(r[0], r[1], wc);
    bfly_dit(r[2], r[3], wc);
    bfly_dit(r[0], r[2], tw[o * (32 / S)]);
    bfly_dit(r[1], r[3], tw[(o + S) * (32 / S)]);
}

// SoA store/load of one float2
__device__ __forceinline__ void stf(float* bx, float* by, int a, float2 v) {
    bx[a] = v.x; by[a] = v.y;
}
__device__ __forceinline__ float2 ldf(const float* bx, const float* by, int a) {
    return make_float2(bx[a], by[a]);
}

// Crew exchange over all 8 register-lines. Crew g owns LDS lines 2g, 2g+1
// per plane; rounds m handle regs (m, m+4). Crew = 32 consecutive lanes of
// one wave -> wave_barrier suffices; DS pipe is in-order per wave.
__device__ __forceinline__ void xch8(float* Xp, float* Yp, int g,
                                     const int* iw, const int* ir,
                                     float2 (&r)[8][4]) {
    const int la = 2 * g, lb = 2 * g + 1;
#pragma unroll
    for (int m = 0; m < 4; ++m) {
#pragma unroll
        for (int q = 0; q < 4; ++q) {
            stf(Xp, Yp, pf(la, iw[q]), r[m][q]);
            stf(Xp, Yp, pf(lb, iw[q]), r[m + 4][q]);
        }
        __builtin_amdgcn_wave_barrier();
#pragma unroll
        for (int q = 0; q < 4; ++q) {
            r[m][q]     = ldf(Xp, Yp, pf(la, ir[q]));
            r[m + 4][q] = ldf(Xp, Yp, pf(lb, ir[q]));
        }
        __builtin_amdgcn_wave_barrier();
    }
}

template <int NW, int SW, int NR, int SR>
__device__ __forceinline__ int XC(float* Xp, float* Yp, int g, int j,
                                  float2 (&r)[8][4]) {
    int iw[4], ow, ir[4], orr;
    oidx<NW, SW>(j, iw, ow);
    oidx<NR, SR>(j, ir, orr);
    (void)ow;
    xch8(Xp, Yp, g, iw, ir, r);
    return orr;
}

// Free register 4x4 transpose within each f-block (pure renaming after
// unroll; involution, used by both transpose directions).
__device__ __forceinline__ void xpose44(float2 (&r)[8][4]) {
#pragma unroll
    for (int f0 = 0; f0 < 8; f0 += 4)
#pragma unroll
        for (int a = 0; a < 4; ++a)
#pragma unroll
            for (int bq = a + 1; bq < 4; ++bq) {
                float2 t = r[f0 + a][bq];
                r[f0 + a][bq] = r[f0 + bq][a];
                r[f0 + bq][a] = t;
            }
}

__device__ __forceinline__ void mkF(int j, int* i) {
    i[0] = 2 * j; i[1] = 2 * j + 1; i[2] = 64 + 2 * j; i[3] = 65 + 2 * j;
}
__device__ __forceinline__ void mkF4(int j, int* i) {
    int b = (j >> 4) * 32 + (j & 15);
    i[0] = b; i[1] = b + 16; i[2] = b + 64; i[3] = b + 80;
}

// 2x2 multiplex on feature pair (a = f0, b = f1) with table entry U[0..3]
__device__ __forceinline__ void muxop(const float2* __restrict__ U,
                                      float2& a, float2& b) {
    float2 p0 = a, p1 = b;
    a = cadd(cmul(U[0], p0), cmul(U[1], p1));
    b = cadd(cmul(U[2], p0), cmul(U[3], p1));
}

// --- Transpose A: Y-pass -> X-pass. Source standard layout, positions
// is[4] (current Y-ownership). Chunk c=(fc,h) writes regs fc*4+2h+{0,1}
// into LDS [Xl][Y] (rotation swizzle), then refills the SAME two phys
// first-indices with the new X-positions q' in {2h,2h+1}.
// MODE 0: q'-position X = j+32q' (Xl = j+32e) -> pass starts at oidx<128,32>.
// MODE 1: q'-position X = 64h+2j+e (Xl = 2j+e) -> pass starts at F.
// Ends with xpose44 -> standard layout.
template <int MODE>
__device__ __forceinline__ void tposeA(float* Xp, float* Yp, int g, int j,
                                       const int* is, float2 (&r)[8][4]) {
#pragma unroll
    for (int c = 0; c < 4; ++c) {
        const int fc = c >> 1, h = c & 1;
        __syncthreads();
#pragma unroll
        for (int e = 0; e < 2; ++e) {
            const int k = fc * 4 + 2 * h + e;
            const int Xl = g + 32 * e;   // line X = 64h + g + 32e
#pragma unroll
            for (int q = 0; q < 4; ++q) {
                int a = Xl * P_ + ((is[q] + Xl) & 127);
                Xp[a] = r[k][q].x; Yp[a] = r[k][q].y;
            }
        }
        __syncthreads();
#pragma unroll
        for (int e = 0; e < 2; ++e) {
            const int Xl = (MODE == 0) ? (j + 32 * e) : (2 * j + e);
#pragma unroll
            for (int d = 0; d < 4; ++d) {
                int a = Xl * P_ + ((g + 32 * d + Xl) & 127);
                r[fc * 4 + 2 * h + e][d] = make_float2(Xp[a], Yp[a]);
            }
        }
    }
    __syncthreads();
    xpose44(r);
}

// --- Transpose B: X-pass -> Y-pass. xpose44 first (standard -> swapped);
// source X-ownership is[4] must have position q in X-half q>>1 (F / F4).
// Dest fills standard slots r[fc*4+dx][qy] at Y-positions id[4].
__device__ __forceinline__ void tposeB(float* Xp, float* Yp, int g, int j,
                                       const int* is, const int* id,
                                       float2 (&r)[8][4]) {
    xpose44(r);
#pragma unroll
    for (int c = 0; c < 4; ++c) {
        const int fc = c >> 1, h = c & 1;
        __syncthreads();
#pragma unroll
        for (int e = 0; e < 2; ++e) {
            const int q = 2 * h + e;
            const int Xl = is[q] & 63;
#pragma unroll
            for (int d = 0; d < 4; ++d) {
                int a = Xl * P_ + ((g + 32 * d + Xl) & 127);
                float2 v = r[fc * 4 + q][d];
                Xp[a] = v.x; Yp[a] = v.y;
            }
        }
        __syncthreads();
#pragma unroll
        for (int e = 0; e < 2; ++e) {
            const int Xl = g + 32 * e;   // dest line X = 64h + g + 32e
#pragma unroll
            for (int qy = 0; qy < 4; ++qy) {
                int a = Xl * P_ + ((id[qy] + Xl) & 127);
                r[fc * 4 + 2 * h + e][qy] = make_float2(Xp[a], Yp[a]);
            }
        }
    }
    __syncthreads();
}

// ---------------------------------------------------------------------------
// K0: precompute multiplex U tables, pre-permuted by bit-reversal.
//   U0: TRANSPOSED  idx = y_st*128 + x_st
//   U1: unchanged   idx = ((cx*2+cy)*64 + xam)*64 + yam
//   U2: TRANSPOSED  idx = ((yam*2 + cx)*2 + cy)*32 + xam
// ---------------------------------------------------------------------------
__global__ __launch_bounds__(256) void k0_prep(const float* __restrict__ mux0,
                                               const float* __restrict__ mux1,
                                               const float* __restrict__ mux2,
                                               float2* __restrict__ U0,
                                               float2* __restrict__ U1,
                                               float2* __restrict__ U2) {
    int t = blockIdx.x * 256 + threadIdx.x;
    const float* src;
    float2* dst;
    if (t < 16384) {
        int xb = t >> 7, yb = t & 127;
        int rx = __brev((unsigned)xb) >> 25;
        int ry = __brev((unsigned)yb) >> 25;
        src = mux0 + ((size_t)rx * 128 + ry) * 3;
        dst = U0 + ((size_t)yb * 128 + xb) * 4;
    } else if (t < 32768) {
        int u = t - 16384;
        int yam = u & 63, xam = (u >> 6) & 63, cy = (u >> 12) & 1, cx = (u >> 13) & 1;
        int rx = __brev((unsigned)xam) >> 26;
        int ry = __brev((unsigned)yam) >> 26;
        src = mux1 + ((size_t)(((cx * 2 + cy) * 64 + rx) * 64 + ry)) * 3;
        dst = U1 + (size_t)u * 4;
    } else if (t < 36864) {
        int u = t - 32768;
        int yam = u & 31, xam = (u >> 5) & 31, cy = (u >> 10) & 1, cx = (u >> 11) & 1;
        int rx = __brev((unsigned)xam) >> 27;
        int ry = __brev((unsigned)yam) >> 27;
        src = mux2 + ((size_t)(((cx * 2 + cy) * 32 + rx) * 32 + ry)) * 3;
        dst = U2 + ((size_t)(((yam * 2 + cx) * 2 + cy) * 32 + xam)) * 4;
    } else {
        return;
    }
    float ax = src[0], ay = src[1], az = src[2];
    float r = sqrtf(ax * ax + ay * ay + az * az + 1e-20f);
    float cr = cosf(r);
    float snr = sinf(r) / r;
    dst[0] = make_float2(cr, -az * snr);
    dst[1] = make_float2(-ay * snr, -ax * snr);
    dst[2] = make_float2(ay * snr, -ax * snr);
    dst[3] = make_float2(cr, az * snr);
}

// ---------------------------------------------------------------------------
// KFUSE: whole pipeline per image INCLUDING the linear head. 1024 threads.
// Round-3 body (arrays, dynamic LDS, __sinf) + 4x-parallel fused head.
// Image loads NONTEMPORAL (streamed once; keep L2 for the scratch traffic).
// ---------------------------------------------------------------------------
__global__ __launch_bounds__(1024, 1)
void kfuse(const float* __restrict__ img,
           const float2* __restrict__ U0,
           const float2* __restrict__ U1,
           const float2* __restrict__ U2,
           const float* __restrict__ W,
           const float* __restrict__ bv,
           float* __restrict__ out) {
    extern __shared__ float smem[];
    float* Xp = smem;                       // 8192 floats
    float* Yp = smem + 8192;                // 8192 floats
    float2* tw = (float2*)(smem + 16384);   // 64 float2

    const int tid = threadIdx.x;
    const int b = blockIdx.x;
    const int g = tid >> 5;
    const int j = tid & 31;

    if (tid < 64) {
        // native sin/cos: |angle| < 2*pi, no reduction needed
        float ang = -(2.0f * PI_F / 128.0f) * (float)tid;
        tw[tid] = make_float2(__cosf(ang), __sinf(ang));
    }

    float2 r[8][4];
    int o;

    // ================= pass 1 (Y): FRQI encode + FFT_Y128 =================
    {
        const float* ib = img + (size_t)b * 16384;
#pragma unroll
        for (int k = 0; k < 4; ++k) {
            const float* ip = ib + (g + 32 * k) * 128;
#pragma unroll
            for (int q = 0; q < 4; ++q) {
                float v = __builtin_nontemporal_load(ip + j + 32 * q);
                float ang = 0.5f * PI_F * v;      // in [0, pi/2)
                float c = __cosf(ang), s = __sinf(ang);  // native, call-free
                r[k][q]     = make_float2(c * (1.0f / 128.0f), 0.0f);  // f=0
                r[k + 4][q] = make_float2(s * (1.0f / 128.0f), 0.0f);  // f=1
            }
        }
    }
    __syncthreads();  // tw visible
#pragma unroll
    for (int k = 0; k < 8; ++k) dif_pair<32>(r[k], j, tw);            // h=64,32
    o = XC<128, 32, 128, 8>(Xp, Yp, g, j, r);
#pragma unroll
    for (int k = 0; k < 8; ++k) dif_pair<8>(r[k], o, tw);             // h=16,8
    o = XC<128, 8, 128, 2>(Xp, Yp, g, j, r);
#pragma unroll
    for (int k = 0; k < 8; ++k) dif_pair<2>(r[k], o, tw);             // h=4,2
    o = XC<128, 2, 128, 1>(Xp, Yp, g, j, r);
#pragma unroll
    for (int k = 0; k < 8; ++k) { bfly_dif1(r[k][0], r[k][1]); bfly_dif1(r[k][2], r[k][3]); }

    // ================= T_A1 =================
    {
        int is[4] = {4 * j, 4 * j + 1, 4 * j + 2, 4 * j + 3};
        tposeA<0>(Xp, Yp, g, j, is, r);
    }

    // ====== pass 2 (X): FFT_X128 -> M0 -> IFFT_X128 -> FFT_X64 ======
#pragma unroll
    for (int k = 0; k < 8; ++k) dif_pair<32>(r[k], j, tw);
    o = XC<128, 32, 128, 8>(Xp, Yp, g, j, r);
#pragma unroll
    for (int k = 0; k < 8; ++k) dif_pair<8>(r[k], o, tw);
    o = XC<128, 8, 128, 2>(Xp, Yp, g, j, r);
#pragma unroll
    for (int k = 0; k < 8; ++k) dif_pair<2>(r[k], o, tw);
    o = XC<128, 2, 128, 1>(Xp, Yp, g, j, r);
#pragma unroll
    for (int k = 0; k < 8; ++k) { bfly_dif1(r[k][0], r[k][1]); bfly_dif1(r[k][2], r[k][3]); }
    // M0 at x_st = 4j+q, y_st = g+32k (register-local f pair!)
#pragma unroll
    for (int k = 0; k < 4; ++k) {
        const float2* Ub = U0 + ((size_t)(g + 32 * k) * 128 + 4 * j) * 4;
#pragma unroll
        for (int q = 0; q < 4; ++q) muxop(Ub + (size_t)q * 4, r[k][q], r[k + 4][q]);
    }
    // IFFT_X128: [1,2] -> [4,8] -> [16,32] -> [64]
#pragma unroll
    for (int k = 0; k < 8; ++k) dit_pair<1>(r[k], 0, tw);
    o = XC<128, 1, 128, 4>(Xp, Yp, g, j, r);
#pragma unroll
    for (int k = 0; k < 8; ++k) dit_pair<4>(r[k], o, tw);
    o = XC<128, 4, 128, 16>(Xp, Yp, g, j, r);
#pragma unroll
    for (int k = 0; k < 8; ++k) dit_pair<16>(r[k], o, tw);
    o = XC<128, 16, 128, 32>(Xp, Yp, g, j, r);
#pragma unroll
    for (int k = 0; k < 8; ++k) { bfly_dit(r[k][0], r[k][2], tw[o]); bfly_dit(r[k][1], r[k][3], tw[o + 32]); }
    // fused FFT64 h=32 (per 64-half), o = j
#pragma unroll
    for (int k = 0; k < 8; ++k) { float2 w = tw[2 * o]; bfly_dif(r[k][0], r[k][1], w); bfly_dif(r[k][2], r[k][3], w); }
    o = XC<128, 32, 64, 8>(Xp, Yp, g, j, r);
#pragma unroll
    for (int k = 0; k < 8; ++k) dif_pair<8>(r[k], o, tw);             // h=16,8
    o = XC<64, 8, 64, 2>(Xp, Yp, g, j, r);
#pragma unroll
    for (int k = 0; k < 8; ++k) dif_pair<2>(r[k], o, tw);             // h=4,2
    {   // -> F ownership (2 positions per 64-half, needed by T_B1)
        int iw_[4], o_, ir_[4];
        oidx<64, 2>(j, iw_, o_);
        mkF(j, ir_);
        xch8(Xp, Yp, g, iw_, ir_, r);
    }
#pragma unroll
    for (int k = 0; k < 8; ++k) {
        bfly_dif1(r[k][0], r[k][1]); bfly_dif1(r[k][2], r[k][3]);     // h=1
        const float sc = 1.0f / 128.0f;                               // IFFT128 norm
#pragma unroll
        for (int q = 0; q < 4; ++q) r[k][q] = scl(r[k][q], sc);
    }

    // ================= T_B1 =================
    {
        int is[4], id[4];
        mkF(j, is);
        id[0] = 4 * j; id[1] = 4 * j + 1; id[2] = 4 * j + 2; id[3] = 4 * j + 3;
        tposeB(Xp, Yp, g, j, is, id, r);
    }

    // == pass 3 (Y): IFFT_Y128 -> FFT_Y64 -> M1 -> IFFT_Y64 -> FFT_Y32 ==
#pragma unroll
    for (int k = 0; k < 8; ++k) dit_pair<1>(r[k], 0, tw);
    o = XC<128, 1, 128, 4>(Xp, Yp, g, j, r);
#pragma unroll
    for (int k = 0; k < 8; ++k) dit_pair<4>(r[k], o, tw);
    o = XC<128, 4, 128, 16>(Xp, Yp, g, j, r);
#pragma unroll
    for (int k = 0; k < 8; ++k) dit_pair<16>(r[k], o, tw);
    o = XC<128, 16, 128, 32>(Xp, Yp, g, j, r);
#pragma unroll
    for (int k = 0; k < 8; ++k) { bfly_dit(r[k][0], r[k][2], tw[o]); bfly_dit(r[k][1], r[k][3], tw[o + 32]); }
#pragma unroll
    for (int k = 0; k < 8; ++k) { float2 w = tw[2 * o]; bfly_dif(r[k][0], r[k][1], w); bfly_dif(r[k][2], r[k][3], w); }
    o = XC<128, 32, 64, 8>(Xp, Yp, g, j, r);
#pragma unroll
    for (int k = 0; k < 8; ++k) dif_pair<8>(r[k], o, tw);
    o = XC<64, 8, 64, 2>(Xp, Yp, g, j, r);
#pragma unroll
    for (int k = 0; k < 8; ++k) dif_pair<2>(r[k], o, tw);
    o = XC<64, 2, 64, 1>(Xp, Yp, g, j, r);
#pragma unroll
    for (int k = 0; k < 8; ++k) { bfly_dif1(r[k][0], r[k][1]); bfly_dif1(r[k][2], r[k][3]); }
    // M1 at E1: y_st = s*64 + 4jj + q; lines x_st = g+32k
    {
        const int s = j >> 4, jj = j & 15;
#pragma unroll
        for (int k = 0; k < 4; ++k) {
            const int cx = k >> 1;
            const int xam = g + 32 * (k & 1);
            const float2* Ub =
                U1 + ((size_t)((((((cx << 1) | s) << 6) | xam) << 6) | (4 * jj))) * 4;
#pragma unroll
            for (int q = 0; q < 4; ++q) muxop(Ub + (size_t)q * 4, r[k][q], r[k + 4][q]);
        }
    }
    // IFFT_Y64: [1,2] -> [4,8] -> [16,32]
#pragma unroll
    for (int k = 0; k < 8; ++k) dit_pair<1>(r[k], 0, tw);
    o = XC<64, 1, 64, 4>(Xp, Yp, g, j, r);
#pragma unroll
    for (int k = 0; k < 8; ++k) dit_pair<4>(r[k], o, tw);
    o = XC<64, 4, 64, 16>(Xp, Yp, g, j, r);
#pragma unroll
    for (int k = 0; k < 8; ++k) dit_pair<16>(r[k], o, tw);
    // fused FFT32 h=16 (o = jj at E16)
#pragma unroll
    for (int k = 0; k < 8; ++k) { float2 w = tw[4 * o]; bfly_dif(r[k][0], r[k][1], w); bfly_dif(r[k][2], r[k][3], w); }
    o = XC<64, 16, 32, 4>(Xp, Yp, g, j, r);
#pragma unroll
    for (int k = 0; k < 8; ++k) dif_pair<4>(r[k], o, tw);             // h=8,4
    o = XC<32, 4, 32, 1>(Xp, Yp, g, j, r);
#pragma unroll
    for (int k = 0; k < 8; ++k) {
        dif_pair<1>(r[k], 0, tw);                                     // h=2,1
        const float sc = 1.0f / 8192.0f;                              // IFFT128*IFFT64
#pragma unroll
        for (int q = 0; q < 4; ++q) r[k][q] = scl(r[k][q], sc);
    }

    // ================= T_A2 (dest positions = F) =================
    {
        int is[4], o_;
        oidx<32, 1>(j, is, o_);
        tposeA<1>(Xp, Yp, g, j, is, r);
    }

    // ====== pass 4 (X): IFFT_X64 -> FFT_X32 -> M2 -> IFFT_X32 ======
    // start at F: h=1 pairs (2j,2j+1), (64+2j, 64+2j+1), w=1
#pragma unroll
    for (int k = 0; k < 8; ++k) { bfly_dit1(r[k][0], r[k][1]); bfly_dit1(r[k][2], r[k][3]); }
    {
        int iw_[4], ir_[4], o_;
        mkF(j, iw_);
        oidx<64, 2>(j, ir_, o_);
        xch8(Xp, Yp, g, iw_, ir_, r);
        o = o_;
    }
#pragma unroll
    for (int k = 0; k < 8; ++k) dit_pair<2>(r[k], o, tw);             // h=2,4
    o = XC<64, 2, 64, 8>(Xp, Yp, g, j, r);
#pragma unroll
    for (int k = 0; k < 8; ++k) dit_pair<8>(r[k], o, tw);             // h=8,16
    o = XC<64, 8, 64, 16>(Xp, Yp, g, j, r);
#pragma unroll
    for (int k = 0; k < 8; ++k) { bfly_dit(r[k][0], r[k][2], tw[2 * o]); bfly_dit(r[k][1], r[k][3], tw[2 * (o + 16)]); }  // h=32
    // fused FFT32 h=16
#pragma unroll
    for (int k = 0; k < 8; ++k) { float2 w = tw[4 * o]; bfly_dif(r[k][0], r[k][1], w); bfly_dif(r[k][2], r[k][3], w); }
    o = XC<64, 16, 32, 4>(Xp, Yp, g, j, r);
#pragma unroll
    for (int k = 0; k < 8; ++k) dif_pair<4>(r[k], o, tw);
    o = XC<32, 4, 32, 1>(Xp, Yp, g, j, r);
#pragma unroll
    for (int k = 0; k < 8; ++k) dif_pair<1>(r[k], 0, tw);
    // M2 at D1: x_st = s4*32 + 4jj8 + q; lines y_st = g+32k
    {
        const int s4 = j >> 3, jj8 = j & 7;
#pragma unroll
        for (int k = 0; k < 4; ++k) {
            const float2* Ub =
                U2 + ((size_t)((((g << 2) | ((s4 & 1) << 1) | (k & 1)) << 5) | (4 * jj8))) * 4;
#pragma unroll
            for (int q = 0; q < 4; ++q) muxop(Ub + (size_t)q * 4, r[k][q], r[k + 4][q]);
        }
    }
    // IFFT_X32: [1,2] -> [4,8] -> [16] (end at F4 for T_B2)
#pragma unroll
    for (int k = 0; k < 8; ++k) dit_pair<1>(r[k], 0, tw);
    o = XC<32, 1, 32, 4>(Xp, Yp, g, j, r);
#pragma unroll
    for (int k = 0; k < 8; ++k) dit_pair<4>(r[k], o, tw);
    {
        int iw_[4], o_, ir_[4];
        oidx<32, 4>(j, iw_, o_);
        mkF4(j, ir_);
        xch8(Xp, Yp, g, iw_, ir_, r);
    }
    {
        const int m = j & 15;
#pragma unroll
        for (int k = 0; k < 8; ++k) {
            float2 w = tw[4 * m];                                     // h=16
            bfly_dit(r[k][0], r[k][1], w);
            bfly_dit(r[k][2], r[k][3], w);
            const float sc = 1.0f / 2048.0f;                          // IFFT64*IFFT32
#pragma unroll
            for (int q = 0; q < 4; ++q) r[k][q] = scl(r[k][q], sc);
        }
    }

    // ================= T_B2 =================
    {
        int is[4], id[4], o_;
        mkF4(j, is);
        oidx<32, 1>(j, id, o_);
        tposeB(Xp, Yp, g, j, is, id, r);
    }

    // ========== pass 5 (Y): IFFT_Y32 + |.|^2 marginal ==========
#pragma unroll
    for (int k = 0; k < 8; ++k) dit_pair<1>(r[k], 0, tw);
    o = XC<32, 1, 32, 4>(Xp, Yp, g, j, r);
#pragma unroll
    for (int k = 0; k < 8; ++k) dit_pair<4>(r[k], o, tw);
    o = XC<32, 4, 32, 8>(Xp, Yp, g, j, r);
#pragma unroll
    for (int k = 0; k < 8; ++k) { bfly_dit(r[k][0], r[k][2], tw[4 * o]); bfly_dit(r[k][1], r[k][3], tw[4 * o + 32]); }  // h=16
    // prob + FUSED LINEAR HEAD (4x-parallel: replica groups split classes).
    // flat prob index (per image): g*64 + (jj + 8q)*2 + f, with p2[f][q]*C.
    {
        float p2[2][4];
#pragma unroll
        for (int f = 0; f < 2; ++f)
#pragma unroll
            for (int q = 0; q < 4; ++q) {
                float s = 0.0f;
#pragma unroll
                for (int d = 0; d < 4; ++d) {
                    float2 v = r[f * 4 + d][q];
                    s += v.x * v.x + v.y * v.y;
                }
                s += __shfl_xor(s, 8);
                s += __shfl_xor(s, 16);
                p2[f][q] = s;   // replicated across the 4 replica groups
            }
        // reuse the (retired) exchange LDS as reduction scratch
        float* redf = smem;
        __syncthreads();   // all prior LDS ops done before reuse
        {
            const float C = 1.0f / 1024.0f;
            const int jj = j & 7, rep = j >> 3;
            // classes per replica group: {0,1,2} {3,4,5} {6,7} {8,9}
            const int c0 = (rep < 2) ? rep * 3 : 6 + (rep - 2) * 2;
            const int nc = (rep < 2) ? 3 : 2;
            const float* Wb = W + g * 64 + jj * 2;
            const float* w0 = Wb + (size_t)c0 * 2048;
            const float* w1 = w0 + 2048;
            // clamp third row to class 9 (never OOB; only written if nc==3)
            const float* w2 = Wb + (size_t)((nc == 3) ? (c0 + 2) : 9) * 2048;
            float d0, d1, d2;
#define DOTC(PTR) (C * (p2[0][0] * (PTR)[0]  + p2[1][0] * (PTR)[1]  + \
                        p2[0][1] * (PTR)[16] + p2[1][1] * (PTR)[17] + \
                        p2[0][2] * (PTR)[32] + p2[1][2] * (PTR)[33] + \
                        p2[0][3] * (PTR)[48] + p2[1][3] * (PTR)[49]))
            d0 = DOTC(w0);
            d1 = DOTC(w1);
            d2 = DOTC(w2);
#undef DOTC
#define RED8(DC) { DC += __shfl_down(DC, 4, 8); DC += __shfl_down(DC, 2, 8); \
                   DC += __shfl_down(DC, 1, 8); }
            RED8(d0) RED8(d1) RED8(d2)
#undef RED8
            if (jj == 0) {
                float* rg = redf + g * 10 + c0;
                rg[0] = d0;
                rg[1] = d1;
                if (nc == 3) rg[2] = d2;
            }
        }
        __syncthreads();
        if (tid < 10) {
            float s = bv[tid];
            for (int g2 = 0; g2 < 32; ++g2) s += redf[g2 * 10 + tid];
            out[b * 10 + tid] = s;
        }
    }
}

// ---------------------------------------------------------------------------
extern "C" void kernel_launch(void* const* d_in, const int* in_sizes, int n_in,
                              void* d_out, int out_size, void* d_ws,
                              size_t ws_size, hipStream_t stream) {
    const float* images = (const float*)d_in[0];
    const float* mux0 = (const float*)d_in[1];
    const float* mux1 = (const float*)d_in[2];
    const float* mux2 = (const float*)d_in[3];
    const float* W = (const float*)d_in[4];
    const float* bv = (const float*)d_in[5];
    float* out = (float*)d_out;

    float2* U0 = (float2*)d_ws;
    float2* U1 = U0 + 65536;
    float2* U2 = U1 + 65536;
    const size_t needed = (size_t)(65536 + 65536 + 16384) * sizeof(float2);
    if (ws_size < needed) return;

    const int LDS_BYTES = (16384 + 128) * 4;  // Xp|Yp planes + tw = 66048 B

    k0_prep<<<144, 256, 0, stream>>>(mux0, mux1, mux2, U0, U1, U2);
    kfuse<<<512, 1024, LDS_BYTES, stream>>>(images, U0, U1, U2, W, bv, out);
}

// Round 13
// 339.127 us; speedup vs baseline: 1.0209x; 1.0209x over previous
//
#include <hip/hip_runtime.h>
#include <math.h>

// ===========================================================================
// PCSQCNN fully fused: FRQI encode -> [QFT2D -> mux -> IQFT2D -> pool]^3
//                      -> |.|^2 -> linear   (linear head fused)
//
// FINAL (round 22 = consolidation on round 19, the measured best: 339.8us).
// Session summary:
//  - k1..k5 fused into ONE kernel (state in 32 float2/thread), k6 fused
//    into the tail: 5 launches -> 2, prob round-trip eliminated.
//  - Toolchain constraint (8 levers, all null): 1024-thread workgroups get
//    a hard 64-VGPR grant -> ~256B/thread state round-trips scratch
//    (~230MB/dispatch), partially hidden by 2 WG/CU (dynamic 66KB LDS).
//  - LDS b64 conversion regressed (VGPR-pair pressure tripled scratch);
//    nontemporal loads, parallel tail, occupancy pins: all within noise.
//  - Floor arithmetic: ~150us VALU issue + scratch-latency stalls at
//    2 WG/CU => kfuse ~293us. Past this requires a no-scratch LDS-park
//    rewrite (16 fl2/thread regs + 128KB park) - out of session scope.
//
// U tables (k0): U0 transposed [y_st][x_st]; U1 unchanged;
// U2 stored [yam][cx][cy][xam]. Ownerships: F = {2j,2j+1,64+2j,65+2j};
// F4 = {fb,fb+16,fb+64,fb+80}, fb=(j>>4)*32+(j&15).
// ===========================================================================

#define PI_F 3.14159265358979323846f
#define P_ 128

__device__ __forceinline__ float2 cmul(float2 a, float2 b) {
    return make_float2(a.x * b.x - a.y * b.y, a.x * b.y + a.y * b.x);
}
__device__ __forceinline__ float2 cadd(float2 a, float2 b) {
    return make_float2(a.x + b.x, a.y + b.y);
}
__device__ __forceinline__ float2 scl(float2 a, float s) {
    return make_float2(a.x * s, a.y * s);
}
// DIF butterfly: u' = u+v ; v' = (u-v)*w
__device__ __forceinline__ void bfly_dif(float2& u, float2& v, float2 w) {
    float tx = u.x - v.x, ty = u.y - v.y;
    u.x += v.x; u.y += v.y;
    v.x = tx * w.x - ty * w.y;
    v.y = tx * w.y + ty * w.x;
}
__device__ __forceinline__ void bfly_dif1(float2& u, float2& v) {
    float tx = u.x - v.x, ty = u.y - v.y;
    u.x += v.x; u.y += v.y;
    v.x = tx; v.y = ty;
}
// DIT inverse butterfly: t = v*conj(w); u' = u+t ; v' = u-t
__device__ __forceinline__ void bfly_dit(float2& u, float2& v, float2 w) {
    float tx = v.x * w.x + v.y * w.y, ty = v.y * w.x - v.x * w.y;
    v.x = u.x - tx; v.y = u.y - ty;
    u.x += tx; u.y += ty;
}
__device__ __forceinline__ void bfly_dit1(float2& u, float2& v) {
    float tx = v.x, ty = v.y;
    v.x = u.x - tx; v.y = u.y - ty;
    u.x += tx; u.y += ty;
}

constexpr int clog2(int v) { return v <= 1 ? 0 : 1 + clog2(v >> 1); }

// LDS exchange address: line L (0..63 per plane), idx 0..127, XOR bank
// swizzle (bijective; GF(2)-rank-verified for all ownership patterns).
__device__ __forceinline__ int pf(int L, int idx) {
    int m = ((idx & 32) ? 13 : 0) ^ ((idx & 64) ? 22 : 0);
    return L * P_ + (idx ^ m);
}

// Ownership: segment size N (<=128), stride S. Thread j (0..31 per line) owns
// idx[q] = seg*N + 4S*(jj/S) + (jj%S) + S*q.  o = jj%S (twiddle low part).
template <int N, int S>
__device__ __forceinline__ void oidx(int j, int i[4], int& o) {
    constexpr int TPS = N / 4;
    constexpr int LT = clog2(TPS);
    int s = j >> LT;
    int jj = j & (TPS - 1);
    o = jj & (S - 1);
    int base = s * N + ((jj & ~(S - 1)) << 2) + o;
    i[0] = base; i[1] = base + S; i[2] = base + 2 * S; i[3] = base + 3 * S;
}

// Two DIF levels h=2S then h=S on r[0..3] (ownership stride S)
template <int S>
__device__ __forceinline__ void dif_pair(float2 r[4], int o, const float2* tw) {
    bfly_dif(r[0], r[2], tw[o * (32 / S)]);
    bfly_dif(r[1], r[3], tw[(o + S) * (32 / S)]);
    float2 wc = tw[o * (64 / S)];
    bfly_dif(r[0], r[1], wc);
    bfly_dif(r[2], r[3], wc);
}
// Two DIT levels h=S then h=2S
template <int S>
__device__ __forceinline__ void dit_pair(float2 r[4], int o, const float2* tw) {
    float2 wc = tw[o * (64 / S)];
    bfly_dit(r[0], r[1], wc);
    bfly_dit(r[2], r[3], wc);
    bfly_dit(r[0], r[2], tw[o * (32 / S)]);
    bfly_dit(r[1], r[3], tw[(o + S) * (32 / S)]);
}

// SoA store/load of one float2
__device__ __forceinline__ void stf(float* bx, float* by, int a, float2 v) {
    bx[a] = v.x; by[a] = v.y;
}
__device__ __forceinline__ float2 ldf(const float* bx, const float* by, int a) {
    return make_float2(bx[a], by[a]);
}

// Crew exchange over all 8 register-lines. Crew g owns LDS lines 2g, 2g+1
// per plane; rounds m handle regs (m, m+4). Crew = 32 consecutive lanes of
// one wave -> wave_barrier suffices; DS pipe is in-order per wave.
__device__ __forceinline__ void xch8(float* Xp, float* Yp, int g,
                                     const int* iw, const int* ir,
                                     float2 (&r)[8][4]) {
    const int la = 2 * g, lb = 2 * g + 1;
#pragma unroll
    for (int m = 0; m < 4; ++m) {
#pragma unroll
        for (int q = 0; q < 4; ++q) {
            stf(Xp, Yp, pf(la, iw[q]), r[m][q]);
            stf(Xp, Yp, pf(lb, iw[q]), r[m + 4][q]);
        }
        __builtin_amdgcn_wave_barrier();
#pragma unroll
        for (int q = 0; q < 4; ++q) {
            r[m][q]     = ldf(Xp, Yp, pf(la, ir[q]));
            r[m + 4][q] = ldf(Xp, Yp, pf(lb, ir[q]));
        }
        __builtin_amdgcn_wave_barrier();
    }
}

template <int NW, int SW, int NR, int SR>
__device__ __forceinline__ int XC(float* Xp, float* Yp, int g, int j,
                                  float2 (&r)[8][4]) {
    int iw[4], ow, ir[4], orr;
    oidx<NW, SW>(j, iw, ow);
    oidx<NR, SR>(j, ir, orr);
    (void)ow;
    xch8(Xp, Yp, g, iw, ir, r);
    return orr;
}

// Free register 4x4 transpose within each f-block (pure renaming after
// unroll; involution, used by both transpose directions).
__device__ __forceinline__ void xpose44(float2 (&r)[8][4]) {
#pragma unroll
    for (int f0 = 0; f0 < 8; f0 += 4)
#pragma unroll
        for (int a = 0; a < 4; ++a)
#pragma unroll
            for (int bq = a + 1; bq < 4; ++bq) {
                float2 t = r[f0 + a][bq];
                r[f0 + a][bq] = r[f0 + bq][a];
                r[f0 + bq][a] = t;
            }
}

__device__ __forceinline__ void mkF(int j, int* i) {
    i[0] = 2 * j; i[1] = 2 * j + 1; i[2] = 64 + 2 * j; i[3] = 65 + 2 * j;
}
__device__ __forceinline__ void mkF4(int j, int* i) {
    int b = (j >> 4) * 32 + (j & 15);
    i[0] = b; i[1] = b + 16; i[2] = b + 64; i[3] = b + 80;
}

// 2x2 multiplex on feature pair (a = f0, b = f1) with table entry U[0..3]
__device__ __forceinline__ void muxop(const float2* __restrict__ U,
                                      float2& a, float2& b) {
    float2 p0 = a, p1 = b;
    a = cadd(cmul(U[0], p0), cmul(U[1], p1));
    b = cadd(cmul(U[2], p0), cmul(U[3], p1));
}

// --- Transpose A: Y-pass -> X-pass. Source standard layout, positions
// is[4] (current Y-ownership). Chunk c=(fc,h) writes regs fc*4+2h+{0,1}
// into LDS [Xl][Y] (rotation swizzle), then refills the SAME two phys
// first-indices with the new X-positions q' in {2h,2h+1}.
// MODE 0: q'-position X = j+32q' (Xl = j+32e) -> pass starts at oidx<128,32>.
// MODE 1: q'-position X = 64h+2j+e (Xl = 2j+e) -> pass starts at F.
// Ends with xpose44 -> standard layout.
template <int MODE>
__device__ __forceinline__ void tposeA(float* Xp, float* Yp, int g, int j,
                                       const int* is, float2 (&r)[8][4]) {
#pragma unroll
    for (int c = 0; c < 4; ++c) {
        const int fc = c >> 1, h = c & 1;
        __syncthreads();
#pragma unroll
        for (int e = 0; e < 2; ++e) {
            const int k = fc * 4 + 2 * h + e;
            const int Xl = g + 32 * e;   // line X = 64h + g + 32e
#pragma unroll
            for (int q = 0; q < 4; ++q) {
                int a = Xl * P_ + ((is[q] + Xl) & 127);
                Xp[a] = r[k][q].x; Yp[a] = r[k][q].y;
            }
        }
        __syncthreads();
#pragma unroll
        for (int e = 0; e < 2; ++e) {
            const int Xl = (MODE == 0) ? (j + 32 * e) : (2 * j + e);
#pragma unroll
            for (int d = 0; d < 4; ++d) {
                int a = Xl * P_ + ((g + 32 * d + Xl) & 127);
                r[fc * 4 + 2 * h + e][d] = make_float2(Xp[a], Yp[a]);
            }
        }
    }
    __syncthreads();
    xpose44(r);
}

// --- Transpose B: X-pass -> Y-pass. xpose44 first (standard -> swapped);
// source X-ownership is[4] must have position q in X-half q>>1 (F / F4).
// Dest fills standard slots r[fc*4+dx][qy] at Y-positions id[4].
__device__ __forceinline__ void tposeB(float* Xp, float* Yp, int g, int j,
                                       const int* is, const int* id,
                                       float2 (&r)[8][4]) {
    xpose44(r);
#pragma unroll
    for (int c = 0; c < 4; ++c) {
        const int fc = c >> 1, h = c & 1;
        __syncthreads();
#pragma unroll
        for (int e = 0; e < 2; ++e) {
            const int q = 2 * h + e;
            const int Xl = is[q] & 63;
#pragma unroll
            for (int d = 0; d < 4; ++d) {
                int a = Xl * P_ + ((g + 32 * d + Xl) & 127);
                float2 v = r[fc * 4 + q][d];
                Xp[a] = v.x; Yp[a] = v.y;
            }
        }
        __syncthreads();
#pragma unroll
        for (int e = 0; e < 2; ++e) {
            const int Xl = g + 32 * e;   // dest line X = 64h + g + 32e
#pragma unroll
            for (int qy = 0; qy < 4; ++qy) {
                int a = Xl * P_ + ((id[qy] + Xl) & 127);
                r[fc * 4 + 2 * h + e][qy] = make_float2(Xp[a], Yp[a]);
            }
        }
    }
    __syncthreads();
}

// ---------------------------------------------------------------------------
// K0: precompute multiplex U tables, pre-permuted by bit-reversal.
//   U0: TRANSPOSED  idx = y_st*128 + x_st
//   U1: unchanged   idx = ((cx*2+cy)*64 + xam)*64 + yam
//   U2: TRANSPOSED  idx = ((yam*2 + cx)*2 + cy)*32 + xam
// ---------------------------------------------------------------------------
__global__ __launch_bounds__(256) void k0_prep(const float* __restrict__ mux0,
                                               const float* __restrict__ mux1,
                                               const float* __restrict__ mux2,
                                               float2* __restrict__ U0,
                                               float2* __restrict__ U1,
                                               float2* __restrict__ U2) {
    int t = blockIdx.x * 256 + threadIdx.x;
    const float* src;
    float2* dst;
    if (t < 16384) {
        int xb = t >> 7, yb = t & 127;
        int rx = __brev((unsigned)xb) >> 25;
        int ry = __brev((unsigned)yb) >> 25;
        src = mux0 + ((size_t)rx * 128 + ry) * 3;
        dst = U0 + ((size_t)yb * 128 + xb) * 4;
    } else if (t < 32768) {
        int u = t - 16384;
        int yam = u & 63, xam = (u >> 6) & 63, cy = (u >> 12) & 1, cx = (u >> 13) & 1;
        int rx = __brev((unsigned)xam) >> 26;
        int ry = __brev((unsigned)yam) >> 26;
        src = mux1 + ((size_t)(((cx * 2 + cy) * 64 + rx) * 64 + ry)) * 3;
        dst = U1 + (size_t)u * 4;
    } else if (t < 36864) {
        int u = t - 32768;
        int yam = u & 31, xam = (u >> 5) & 31, cy = (u >> 10) & 1, cx = (u >> 11) & 1;
        int rx = __brev((unsigned)xam) >> 27;
        int ry = __brev((unsigned)yam) >> 27;
        src = mux2 + ((size_t)(((cx * 2 + cy) * 32 + rx) * 32 + ry)) * 3;
        dst = U2 + ((size_t)(((yam * 2 + cx) * 2 + cy) * 32 + xam)) * 4;
    } else {
        return;
    }
    float ax = src[0], ay = src[1], az = src[2];
    float r = sqrtf(ax * ax + ay * ay + az * az + 1e-20f);
    float cr = cosf(r);
    float snr = sinf(r) / r;
    dst[0] = make_float2(cr, -az * snr);
    dst[1] = make_float2(-ay * snr, -ax * snr);
    dst[2] = make_float2(ay * snr, -ax * snr);
    dst[3] = make_float2(cr, az * snr);
}

// ---------------------------------------------------------------------------
// KFUSE: whole pipeline per image INCLUDING the linear head. 1024 threads.
// Round-3 body (arrays, dynamic LDS, __sinf) + fused k6 tail.
// ---------------------------------------------------------------------------
__global__ __attribute__((amdgpu_flat_work_group_size(1024, 1024)))
__attribute__((amdgpu_waves_per_eu(4, 4)))
void kfuse(const float* __restrict__ img,
           const float2* __restrict__ U0,
           const float2* __restrict__ U1,
           const float2* __restrict__ U2,
           const float* __restrict__ W,
           const float* __restrict__ bv,
           float* __restrict__ out) {
    extern __shared__ float smem[];
    float* Xp = smem;                       // 8192 floats
    float* Yp = smem + 8192;                // 8192 floats
    float2* tw = (float2*)(smem + 16384);   // 64 float2

    const int tid = threadIdx.x;
    const int b = blockIdx.x;
    const int g = tid >> 5;
    const int j = tid & 31;

    if (tid < 64) {
        // native sin/cos: |angle| < 2*pi, no reduction needed
        float ang = -(2.0f * PI_F / 128.0f) * (float)tid;
        tw[tid] = make_float2(__cosf(ang), __sinf(ang));
    }

    float2 r[8][4];
    int o;

    // ================= pass 1 (Y): FRQI encode + FFT_Y128 =================
    {
        const float* ib = img + (size_t)b * 16384;
#pragma unroll
        for (int k = 0; k < 4; ++k) {
            const float* ip = ib + (g + 32 * k) * 128;
#pragma unroll
            for (int q = 0; q < 4; ++q) {
                float v = ip[j + 32 * q];
                float ang = 0.5f * PI_F * v;      // in [0, pi/2)
                float c = __cosf(ang), s = __sinf(ang);  // native, call-free
                r[k][q]     = make_float2(c * (1.0f / 128.0f), 0.0f);  // f=0
                r[k + 4][q] = make_float2(s * (1.0f / 128.0f), 0.0f);  // f=1
            }
        }
    }
    __syncthreads();  // tw visible
#pragma unroll
    for (int k = 0; k < 8; ++k) dif_pair<32>(r[k], j, tw);            // h=64,32
    o = XC<128, 32, 128, 8>(Xp, Yp, g, j, r);
#pragma unroll
    for (int k = 0; k < 8; ++k) dif_pair<8>(r[k], o, tw);             // h=16,8
    o = XC<128, 8, 128, 2>(Xp, Yp, g, j, r);
#pragma unroll
    for (int k = 0; k < 8; ++k) dif_pair<2>(r[k], o, tw);             // h=4,2
    o = XC<128, 2, 128, 1>(Xp, Yp, g, j, r);
#pragma unroll
    for (int k = 0; k < 8; ++k) { bfly_dif1(r[k][0], r[k][1]); bfly_dif1(r[k][2], r[k][3]); }

    // ================= T_A1 =================
    {
        int is[4] = {4 * j, 4 * j + 1, 4 * j + 2, 4 * j + 3};
        tposeA<0>(Xp, Yp, g, j, is, r);
    }

    // ====== pass 2 (X): FFT_X128 -> M0 -> IFFT_X128 -> FFT_X64 ======
#pragma unroll
    for (int k = 0; k < 8; ++k) dif_pair<32>(r[k], j, tw);
    o = XC<128, 32, 128, 8>(Xp, Yp, g, j, r);
#pragma unroll
    for (int k = 0; k < 8; ++k) dif_pair<8>(r[k], o, tw);
    o = XC<128, 8, 128, 2>(Xp, Yp, g, j, r);
#pragma unroll
    for (int k = 0; k < 8; ++k) dif_pair<2>(r[k], o, tw);
    o = XC<128, 2, 128, 1>(Xp, Yp, g, j, r);
#pragma unroll
    for (int k = 0; k < 8; ++k) { bfly_dif1(r[k][0], r[k][1]); bfly_dif1(r[k][2], r[k][3]); }
    // M0 at x_st = 4j+q, y_st = g+32k (register-local f pair!)
#pragma unroll
    for (int k = 0; k < 4; ++k) {
        const float2* Ub = U0 + ((size_t)(g + 32 * k) * 128 + 4 * j) * 4;
#pragma unroll
        for (int q = 0; q < 4; ++q) muxop(Ub + (size_t)q * 4, r[k][q], r[k + 4][q]);
    }
    // IFFT_X128: [1,2] -> [4,8] -> [16,32] -> [64]
#pragma unroll
    for (int k = 0; k < 8; ++k) dit_pair<1>(r[k], 0, tw);
    o = XC<128, 1, 128, 4>(Xp, Yp, g, j, r);
#pragma unroll
    for (int k = 0; k < 8; ++k) dit_pair<4>(r[k], o, tw);
    o = XC<128, 4, 128, 16>(Xp, Yp, g, j, r);
#pragma unroll
    for (int k = 0; k < 8; ++k) dit_pair<16>(r[k], o, tw);
    o = XC<128, 16, 128, 32>(Xp, Yp, g, j, r);
#pragma unroll
    for (int k = 0; k < 8; ++k) { bfly_dit(r[k][0], r[k][2], tw[o]); bfly_dit(r[k][1], r[k][3], tw[o + 32]); }
    // fused FFT64 h=32 (per 64-half), o = j
#pragma unroll
    for (int k = 0; k < 8; ++k) { float2 w = tw[2 * o]; bfly_dif(r[k][0], r[k][1], w); bfly_dif(r[k][2], r[k][3], w); }
    o = XC<128, 32, 64, 8>(Xp, Yp, g, j, r);
#pragma unroll
    for (int k = 0; k < 8; ++k) dif_pair<8>(r[k], o, tw);             // h=16,8
    o = XC<64, 8, 64, 2>(Xp, Yp, g, j, r);
#pragma unroll
    for (int k = 0; k < 8; ++k) dif_pair<2>(r[k], o, tw);             // h=4,2
    {   // -> F ownership (2 positions per 64-half, needed by T_B1)
        int iw_[4], o_, ir_[4];
        oidx<64, 2>(j, iw_, o_);
        mkF(j, ir_);
        xch8(Xp, Yp, g, iw_, ir_, r);
    }
#pragma unroll
    for (int k = 0; k < 8; ++k) {
        bfly_dif1(r[k][0], r[k][1]); bfly_dif1(r[k][2], r[k][3]);     // h=1
        const float sc = 1.0f / 128.0f;                               // IFFT128 norm
#pragma unroll
        for (int q = 0; q < 4; ++q) r[k][q] = scl(r[k][q], sc);
    }

    // ================= T_B1 =================
    {
        int is[4], id[4];
        mkF(j, is);
        id[0] = 4 * j; id[1] = 4 * j + 1; id[2] = 4 * j + 2; id[3] = 4 * j + 3;
        tposeB(Xp, Yp, g, j, is, id, r);
    }

    // == pass 3 (Y): IFFT_Y128 -> FFT_Y64 -> M1 -> IFFT_Y64 -> FFT_Y32 ==
#pragma unroll
    for (int k = 0; k < 8; ++k) dit_pair<1>(r[k], 0, tw);
    o = XC<128, 1, 128, 4>(Xp, Yp, g, j, r);
#pragma unroll
    for (int k = 0; k < 8; ++k) dit_pair<4>(r[k], o, tw);
    o = XC<128, 4, 128, 16>(Xp, Yp, g, j, r);
#pragma unroll
    for (int k = 0; k < 8; ++k) dit_pair<16>(r[k], o, tw);
    o = XC<128, 16, 128, 32>(Xp, Yp, g, j, r);
#pragma unroll
    for (int k = 0; k < 8; ++k) { bfly_dit(r[k][0], r[k][2], tw[o]); bfly_dit(r[k][1], r[k][3], tw[o + 32]); }
#pragma unroll
    for (int k = 0; k < 8; ++k) { float2 w = tw[2 * o]; bfly_dif(r[k][0], r[k][1], w); bfly_dif(r[k][2], r[k][3], w); }
    o = XC<128, 32, 64, 8>(Xp, Yp, g, j, r);
#pragma unroll
    for (int k = 0; k < 8; ++k) dif_pair<8>(r[k], o, tw);
    o = XC<64, 8, 64, 2>(Xp, Yp, g, j, r);
#pragma unroll
    for (int k = 0; k < 8; ++k) dif_pair<2>(r[k], o, tw);
    o = XC<64, 2, 64, 1>(Xp, Yp, g, j, r);
#pragma unroll
    for (int k = 0; k < 8; ++k) { bfly_dif1(r[k][0], r[k][1]); bfly_dif1(r[k][2], r[k][3]); }
    // M1 at E1: y_st = s*64 + 4jj + q; lines x_st = g+32k
    {
        const int s = j >> 4, jj = j & 15;
#pragma unroll
        for (int k = 0; k < 4; ++k) {
            const int cx = k >> 1;
            const int xam = g + 32 * (k & 1);
            const float2* Ub =
                U1 + ((size_t)((((((cx << 1) | s) << 6) | xam) << 6) | (4 * jj))) * 4;
#pragma unroll
            for (int q = 0; q < 4; ++q) muxop(Ub + (size_t)q * 4, r[k][q], r[k + 4][q]);
        }
    }
    // IFFT_Y64: [1,2] -> [4,8] -> [16,32]
#pragma unroll
    for (int k = 0; k < 8; ++k) dit_pair<1>(r[k], 0, tw);
    o = XC<64, 1, 64, 4>(Xp, Yp, g, j, r);
#pragma unroll
    for (int k = 0; k < 8; ++k) dit_pair<4>(r[k], o, tw);
    o = XC<64, 4, 64, 16>(Xp, Yp, g, j, r);
#pragma unroll
    for (int k = 0; k < 8; ++k) dit_pair<16>(r[k], o, tw);
    // fused FFT32 h=16 (o = jj at E16)
#pragma unroll
    for (int k = 0; k < 8; ++k) { float2 w = tw[4 * o]; bfly_dif(r[k][0], r[k][1], w); bfly_dif(r[k][2], r[k][3], w); }
    o = XC<64, 16, 32, 4>(Xp, Yp, g, j, r);
#pragma unroll
    for (int k = 0; k < 8; ++k) dif_pair<4>(r[k], o, tw);             // h=8,4
    o = XC<32, 4, 32, 1>(Xp, Yp, g, j, r);
#pragma unroll
    for (int k = 0; k < 8; ++k) {
        dif_pair<1>(r[k], 0, tw);                                     // h=2,1
        const float sc = 1.0f / 8192.0f;                              // IFFT128*IFFT64
#pragma unroll
        for (int q = 0; q < 4; ++q) r[k][q] = scl(r[k][q], sc);
    }

    // ================= T_A2 (dest positions = F) =================
    {
        int is[4], o_;
        oidx<32, 1>(j, is, o_);
        tposeA<1>(Xp, Yp, g, j, is, r);
    }

    // ====== pass 4 (X): IFFT_X64 -> FFT_X32 -> M2 -> IFFT_X32 ======
    // start at F: h=1 pairs (2j,2j+1), (64+2j, 64+2j+1), w=1
#pragma unroll
    for (int k = 0; k < 8; ++k) { bfly_dit1(r[k][0], r[k][1]); bfly_dit1(r[k][2], r[k][3]); }
    {
        int iw_[4], ir_[4], o_;
        mkF(j, iw_);
        oidx<64, 2>(j, ir_, o_);
        xch8(Xp, Yp, g, iw_, ir_, r);
        o = o_;
    }
#pragma unroll
    for (int k = 0; k < 8; ++k) dit_pair<2>(r[k], o, tw);             // h=2,4
    o = XC<64, 2, 64, 8>(Xp, Yp, g, j, r);
#pragma unroll
    for (int k = 0; k < 8; ++k) dit_pair<8>(r[k], o, tw);             // h=8,16
    o = XC<64, 8, 64, 16>(Xp, Yp, g, j, r);
#pragma unroll
    for (int k = 0; k < 8; ++k) { bfly_dit(r[k][0], r[k][2], tw[2 * o]); bfly_dit(r[k][1], r[k][3], tw[2 * (o + 16)]); }  // h=32
    // fused FFT32 h=16
#pragma unroll
    for (int k = 0; k < 8; ++k) { float2 w = tw[4 * o]; bfly_dif(r[k][0], r[k][1], w); bfly_dif(r[k][2], r[k][3], w); }
    o = XC<64, 16, 32, 4>(Xp, Yp, g, j, r);
#pragma unroll
    for (int k = 0; k < 8; ++k) dif_pair<4>(r[k], o, tw);
    o = XC<32, 4, 32, 1>(Xp, Yp, g, j, r);
#pragma unroll
    for (int k = 0; k < 8; ++k) dif_pair<1>(r[k], 0, tw);
    // M2 at D1: x_st = s4*32 + 4jj8 + q; lines y_st = g+32k
    {
        const int s4 = j >> 3, jj8 = j & 7;
#pragma unroll
        for (int k = 0; k < 4; ++k) {
            const float2* Ub =
                U2 + ((size_t)((((g << 2) | ((s4 & 1) << 1) | (k & 1)) << 5) | (4 * jj8))) * 4;
#pragma unroll
            for (int q = 0; q < 4; ++q) muxop(Ub + (size_t)q * 4, r[k][q], r[k + 4][q]);
        }
    }
    // IFFT_X32: [1,2] -> [4,8] -> [16] (end at F4 for T_B2)
#pragma unroll
    for (int k = 0; k < 8; ++k) dit_pair<1>(r[k], 0, tw);
    o = XC<32, 1, 32, 4>(Xp, Yp, g, j, r);
#pragma unroll
    for (int k = 0; k < 8; ++k) dit_pair<4>(r[k], o, tw);
    {
        int iw_[4], o_, ir_[4];
        oidx<32, 4>(j, iw_, o_);
        mkF4(j, ir_);
        xch8(Xp, Yp, g, iw_, ir_, r);
    }
    {
        const int m = j & 15;
#pragma unroll
        for (int k = 0; k < 8; ++k) {
            float2 w = tw[4 * m];                                     // h=16
            bfly_dit(r[k][0], r[k][1], w);
            bfly_dit(r[k][2], r[k][3], w);
            const float sc = 1.0f / 2048.0f;                          // IFFT64*IFFT32
#pragma unroll
            for (int q = 0; q < 4; ++q) r[k][q] = scl(r[k][q], sc);
        }
    }

    // ================= T_B2 =================
    {
        int is[4], id[4], o_;
        mkF4(j, is);
        oidx<32, 1>(j, id, o_);
        tposeB(Xp, Yp, g, j, is, id, r);
    }

    // ========== pass 5 (Y): IFFT_Y32 + |.|^2 marginal ==========
#pragma unroll
    for (int k = 0; k < 8; ++k) dit_pair<1>(r[k], 0, tw);
    o = XC<32, 1, 32, 4>(Xp, Yp, g, j, r);
#pragma unroll
    for (int k = 0; k < 8; ++k) dit_pair<4>(r[k], o, tw);
    o = XC<32, 4, 32, 8>(Xp, Yp, g, j, r);
#pragma unroll
    for (int k = 0; k < 8; ++k) { bfly_dit(r[k][0], r[k][2], tw[4 * o]); bfly_dit(r[k][1], r[k][3], tw[4 * o + 32]); }  // h=16
    // prob + FUSED LINEAR HEAD.
    // flat prob index (per image): g*64 + (jj + 8q)*2 + f, with p2[f][q]*C.
    {
        float p2[2][4];
#pragma unroll
        for (int f = 0; f < 2; ++f)
#pragma unroll
            for (int q = 0; q < 4; ++q) {
                float s = 0.0f;
#pragma unroll
                for (int d = 0; d < 4; ++d) {
                    float2 v = r[f * 4 + d][q];
                    s += v.x * v.x + v.y * v.y;
                }
                s += __shfl_xor(s, 8);
                s += __shfl_xor(s, 16);
                p2[f][q] = s;
            }
        // reuse the (retired) exchange LDS as reduction scratch
        float* redf = smem;
        __syncthreads();   // all prior LDS ops done before reuse
        if ((j >> 3) == 0) {
            const float C = 1.0f / 1024.0f;
            const float* Wb = W + g * 64 + j * 2;
            float d0, d1, d2, d3, d4, d5, d6, d7, d8, d9;
#define DOT_C(CI, DC) { const float* wr = Wb + (CI) * 2048; \
            DC = C * (p2[0][0] * wr[0]  + p2[1][0] * wr[1]  + \
                      p2[0][1] * wr[16] + p2[1][1] * wr[17] + \
                      p2[0][2] * wr[32] + p2[1][2] * wr[33] + \
                      p2[0][3] * wr[48] + p2[1][3] * wr[49]); }
            DOT_C(0, d0) DOT_C(1, d1) DOT_C(2, d2) DOT_C(3, d3) DOT_C(4, d4)
            DOT_C(5, d5) DOT_C(6, d6) DOT_C(7, d7) DOT_C(8, d8) DOT_C(9, d9)
#undef DOT_C
#define RED8(DC) { DC += __shfl_down(DC, 4, 8); DC += __shfl_down(DC, 2, 8); \
                   DC += __shfl_down(DC, 1, 8); }
            RED8(d0) RED8(d1) RED8(d2) RED8(d3) RED8(d4)
            RED8(d5) RED8(d6) RED8(d7) RED8(d8) RED8(d9)
#undef RED8
            if (j == 0) {
                float* rg = redf + g * 10;
                rg[0] = d0; rg[1] = d1; rg[2] = d2; rg[3] = d3; rg[4] = d4;
                rg[5] = d5; rg[6] = d6; rg[7] = d7; rg[8] = d8; rg[9] = d9;
            }
        }
        __syncthreads();
        if (tid < 10) {
            float s = bv[tid];
            for (int g2 = 0; g2 < 32; ++g2) s += redf[g2 * 10 + tid];
            out[b * 10 + tid] = s;
        }
    }
}

// ---------------------------------------------------------------------------
extern "C" void kernel_launch(void* const* d_in, const int* in_sizes, int n_in,
                              void* d_out, int out_size, void* d_ws,
                              size_t ws_size, hipStream_t stream) {
    const float* images = (const float*)d_in[0];
    const float* mux0 = (const float*)d_in[1];
    const float* mux1 = (const float*)d_in[2];
    const float* mux2 = (const float*)d_in[3];
    const float* W = (const float*)d_in[4];
    const float* bv = (const float*)d_in[5];
    float* out = (float*)d_out;

    float2* U0 = (float2*)d_ws;
    float2* U1 = U0 + 65536;
    float2* U2 = U1 + 65536;
    const size_t needed = (size_t)(65536 + 65536 + 16384) * sizeof(float2);
    if (ws_size < needed) return;

    const int LDS_BYTES = (16384 + 128) * 4;  // Xp|Yp planes + tw = 66048 B

    k0_prep<<<144, 256, 0, stream>>>(mux0, mux1, mux2, U0, U1, U2);
    kfuse<<<512, 1024, LDS_BYTES, stream>>>(images, U0, U1, U2, W, bv, out);
}